// Round 1
// 258.946 us; speedup vs baseline: 1.0111x; 1.0111x over previous
//
#include <hip/hip_runtime.h>

#define IN_F 4096
#define OUT_F 11008
#define BATCH 64
#define NT (OUT_F / 16)          // 688 n-tiles / blocks
#define NWAVE 8                  // waves per block
#define SPW (IN_F / 64 / NWAVE)  // 8 K-steps of 64 per wave

typedef int v4i __attribute__((ext_vector_type(4)));
typedef signed char i8;

__device__ __forceinline__ int pack4(int a0, int a1, int a2, int a3) {
    return (a0 & 0xff) | ((a1 & 0xff) << 8) | ((a2 & 0xff) << 16) |
           ((unsigned)a3 << 24);
}

// async global->LDS, 16B per lane, LDS dest = wave-uniform base + lane*16
__device__ __forceinline__ void gload16(const int* g, int* l) {
    __builtin_amdgcn_global_load_lds(
        (const __attribute__((address_space(1))) void*)g,
        (__attribute__((address_space(3))) void*)l, 16, 0, 0);
}

// ---------------------------------------------------------------------------
// quant_x (proven R2-R4 layout): per-row int8 quantization of x into MFMA
// A-fragment order: xq v4i index (s*256 + mt*64 + lane) = A-frag(step s,
// m-tile mt, lane), A[m=lane&15][k=(lane>>4)*16+j].
// Reduction now: 64-lane shfl_xor + 1 barrier (was 8-barrier LDS tree).
// ---------------------------------------------------------------------------
__global__ __launch_bounds__(256)
void quant_x_kernel(const float* __restrict__ x, i8* __restrict__ xq,
                    float* __restrict__ xscale)
{
    const int b = blockIdx.x;
    const int t = threadIdx.x;
    const float* xr = x + (size_t)b * IN_F;
    const int i0 = t * 16;

    float vals[16];
    float m = 0.0f;
#pragma unroll
    for (int j = 0; j < 16; ++j) {
        vals[j] = xr[i0 + j];
        m = fmaxf(m, fabsf(vals[j]));
    }

    // wave64 butterfly reduce, then 4 wave maxes through LDS, 1 barrier
#pragma unroll
    for (int o = 32; o > 0; o >>= 1) m = fmaxf(m, __shfl_xor(m, o));
    __shared__ float wm[4];
    if ((t & 63) == 0) wm[t >> 6] = m;
    __syncthreads();
    const float amax = fmaxf(fmaxf(wm[0], wm[1]), fmaxf(wm[2], wm[3]));

    const float inv = (amax > 0.0f) ? (127.0f / amax) : 0.0f;
    if (t == 0) xscale[b] = (amax > 0.0f) ? (amax / 127.0f) : 1.0f;

    const int kc   = i0 >> 6;
    const int quad = (i0 >> 4) & 3;
    const int mt   = b >> 4;
    const int lane = (b & 15) | (quad << 4);

    i8 q[16];
#pragma unroll
    for (int j = 0; j < 16; ++j) {
        float r = rintf(vals[j] * inv);
        r = fminf(127.0f, fmaxf(-127.0f, r));
        q[j] = (i8)(int)r;
    }
    *(v4i*)(xq + ((size_t)(kc * 256 + mt * 64 + lane) * 16)) = *(const v4i*)q;
}

// ---------------------------------------------------------------------------
// GEMM. Block = n-tile (16 output rows); 8 waves split K into eighths.
// B-path per wave-step (NEW):
//   - 4x global_load_lds dwordx4 into a per-wave LINEAR [16][64]-int tile,
//     with XOR-swizzled per-lane GLOBAL source (chunk c stored at LDS chunk
//     c^(row&7)): same four 256B row-runs per instr => identical coalescing,
//     but the transposed ds_read_b128 phase becomes conflict-free
//     (8 hits/bank wave64 minimum) on the linear tile (rule #21 pattern).
//   - per-wave double buffer (2 x 4KB), counted s_waitcnt vmcnt(12) so the
//     next step's 4 loads + 4 A-frag loads stay in flight (T4: never drain
//     to 0 in the loop). Empty memory-clobber asm fences pin VMEM program
//     order so the count is sound; lgkmcnt(0) after the reads guarantees
//     the in-flight ds_reads drain before the buffer is rewritten.
//   - no ds_write, no VGPR weight staging: ~-32 VGPRs, -12 instrs/step.
// LDS 64KB => 2 blocks/CU; __launch_bounds__(512,4) caps VGPR at 128 so
// residency is LDS-limited, not VGPR-limited.
// Cross-wave int combine in LDS (stride 17), single direct store with bias.
// HBM: 180 MB weights (mandatory: int8 weights arrive as int32) + 1 MB xq
// + 2.8 MB out => ~29 us floor at 6.3 TB/s.
// NOTE for future rounds: measured total includes ~214us of harness poison
// fills (2 x 107us fillBufferAligned @ 6.8 TB/s inside the timed window);
// kernel-controllable budget is only the remaining ~48us.
// ---------------------------------------------------------------------------
__global__ __launch_bounds__(512, 4)
void gemm_kernel(const int* __restrict__ wq, const i8* __restrict__ xq,
                 const float* __restrict__ xscale,
                 const float* __restrict__ wscale,
                 const float* __restrict__ bias,
                 float* __restrict__ out)
{
    __shared__ int lds[NWAVE * 2048];   // per-wave 2 x 1024-dword tiles = 64KB
    const int lane = threadIdx.x & 63;
    const int wave = threadIdx.x >> 6;
    const int nt   = blockIdx.x;
    int* wbuf = lds + wave * 2048;

    const int n    = lane & 15;     // B-fragment n / output col-in-tile
    const int q    = lane >> 4;     // B-fragment k-quad
    const int grow = lane >> 4;     // row-in-group for staging loads
    const int col  = lane & 15;     // 16B-chunk slot in LDS row

    const int s0 = wave * SPW;      // this wave's first K-step
    // per-lane swizzled source chunk offsets (ints):
    // even p: rows r&7 = grow;  odd p: r&7 = grow+4 (grow<4 => grow^4)
    const int ce = (col ^ grow) << 2;
    const int co = (col ^ grow ^ 4) << 2;
    const int* gbase = wq + (size_t)(nt * 16 + grow) * IN_F + s0 * 64;

    const v4i* pA = (const v4i*)xq + (size_t)s0 * 256 + lane;

    v4i acc[4];
#pragma unroll
    for (int mt = 0; mt < 4; ++mt) acc[mt] = (v4i){0, 0, 0, 0};

    v4i aC[4], aN[4];

    // transposed-read offsets (dwords): row n, LDS chunk (q*4+d)^(n&7)
    int roff[4];
#pragma unroll
    for (int d = 0; d < 4; ++d)
        roff[d] = n * 64 + ((((q * 4 + d) ^ (n & 7))) << 2);

    // prologue: stage step 0 into tile 0, load A-frags for step 0
#pragma unroll
    for (int p = 0; p < 4; ++p)
        gload16(gbase + (size_t)(4 * p) * IN_F + ((p & 1) ? co : ce),
                wbuf + p * 256);
    asm volatile("" ::: "memory");
#pragma unroll
    for (int mt = 0; mt < 4; ++mt) aC[mt] = pA[mt * 64];
    asm volatile("" ::: "memory");

#pragma unroll
    for (int ss = 0; ss < SPW; ++ss) {
        const int* cur = wbuf + (ss & 1) * 1024;
        if (ss + 1 < SPW) {
            int* nxt = wbuf + ((ss + 1) & 1) * 1024;
            const int* gs = gbase + (ss + 1) * 64;
#pragma unroll
            for (int p = 0; p < 4; ++p)
                gload16(gs + (size_t)(4 * p) * IN_F + ((p & 1) ? co : ce),
                        nxt + p * 256);
            asm volatile("" ::: "memory");
#pragma unroll
            for (int mt = 0; mt < 4; ++mt)
                aN[mt] = pA[(ss + 1) * 256 + mt * 64];
            asm volatile("" ::: "memory");
            // 12 VMEM ops issued since this step's 4 global_load_lds
            // (4 A-loads prev iter + 4 gll + 4 A-loads this iter) =>
            // vmcnt(12) completes THIS step's tile, keeps next in flight.
            asm volatile("s_waitcnt vmcnt(12)" ::: "memory");
        } else {
            // last step: only this step's 4 A-loads are newer than its tile
            asm volatile("s_waitcnt vmcnt(4)" ::: "memory");
        }

        v4i rd[4];
#pragma unroll
        for (int d = 0; d < 4; ++d)
            rd[d] = *(const v4i*)(cur + roff[d]);
        // drain reads before program-later gll can rewrite this buffer
        asm volatile("s_waitcnt lgkmcnt(0)" ::: "memory");

        v4i bfrag;
#pragma unroll
        for (int d = 0; d < 4; ++d)
            bfrag[d] = pack4(rd[d][0], rd[d][1], rd[d][2], rd[d][3]);

#pragma unroll
        for (int mt = 0; mt < 4; ++mt)
            acc[mt] = __builtin_amdgcn_mfma_i32_16x16x64_i8(aC[mt], bfrag,
                                                            acc[mt], 0, 0, 0);

        if (ss + 1 < SPW) {
#pragma unroll
            for (int mt = 0; mt < 4; ++mt) aC[mt] = aN[mt];
        }
    }

    // combine regions (wave*1088) overlap other waves' tiles => barrier first
    __syncthreads();
#pragma unroll
    for (int mt = 0; mt < 4; ++mt)
#pragma unroll
        for (int r = 0; r < 4; ++r)
            lds[wave * 1088 + lane * 17 + mt * 4 + r] = acc[mt][r];
    __syncthreads();

    // 512 threads -> 1024 outputs: wave pair (mt2, rp) x lane (n, q) x 2 rows
    const int mt2 = wave >> 1;
    const int rp  = (wave & 1) * 2;
    const int o   = nt * 16 + n;
    const float wsc = wscale[o];
    const float bo  = bias[o];
#pragma unroll
    for (int j = 0; j < 2; ++j) {
        const int r = rp + j;
        int s = 0;
#pragma unroll
        for (int w = 0; w < NWAVE; ++w)
            s += lds[w * 1088 + lane * 17 + mt2 * 4 + r];
        const int b = mt2 * 16 + q * 4 + r;   // C/D: row = quad*4 + reg
        out[(size_t)b * OUT_F + o] = (float)s * xscale[b] * wsc + bo;
    }
}

extern "C" void kernel_launch(void* const* d_in, const int* in_sizes, int n_in,
                              void* d_out, int out_size, void* d_ws, size_t ws_size,
                              hipStream_t stream)
{
    const float* x      = (const float*)d_in[0];
    const int*   wq     = (const int*)d_in[1];   // integer inputs arrive as int32
    const float* wscale = (const float*)d_in[2];
    const float* bias   = (const float*)d_in[3];
    float* out = (float*)d_out;

    i8*    xq     = (i8*)d_ws;
    float* xscale = (float*)((char*)d_ws + 256u * 1024u);

    quant_x_kernel<<<BATCH, 256, 0, stream>>>(x, xq, xscale);
    gemm_kernel<<<NT, 512, 0, stream>>>(wq, xq, xscale, wscale, bias, out);
}

// Round 2
// 258.450 us; speedup vs baseline: 1.0131x; 1.0019x over previous
//
#include <hip/hip_runtime.h>

#define IN_F 4096
#define OUT_F 11008
#define BATCH 64
#define NT (OUT_F / 16)          // 688 n-tiles / blocks
#define NWAVE 8                  // waves per block
#define SPW (IN_F / 64 / NWAVE)  // 8 K-steps of 64 per wave

typedef int v4i __attribute__((ext_vector_type(4)));
typedef signed char i8;

__device__ __forceinline__ int pack4(int a0, int a1, int a2, int a3) {
    return (a0 & 0xff) | ((a1 & 0xff) << 8) | ((a2 & 0xff) << 16) |
           ((unsigned)a3 << 24);
}

// ---------------------------------------------------------------------------
// quant_x (proven layout): per-row int8 quantization of x into MFMA A-fragment
// order: xq v4i index (s*256 + mt*64 + lane) = A-frag(step s, m-tile mt, lane),
// A[m=lane&15][k=(lane>>4)*16+j]. shfl_xor reduce + 1 barrier.
// ---------------------------------------------------------------------------
__global__ __launch_bounds__(256)
void quant_x_kernel(const float* __restrict__ x, i8* __restrict__ xq,
                    float* __restrict__ xscale)
{
    const int b = blockIdx.x;
    const int t = threadIdx.x;
    const float* xr = x + (size_t)b * IN_F;
    const int i0 = t * 16;

    float vals[16];
    float m = 0.0f;
#pragma unroll
    for (int j = 0; j < 16; ++j) {
        vals[j] = xr[i0 + j];
        m = fmaxf(m, fabsf(vals[j]));
    }

#pragma unroll
    for (int o = 32; o > 0; o >>= 1) m = fmaxf(m, __shfl_xor(m, o));
    __shared__ float wm[4];
    if ((t & 63) == 0) wm[t >> 6] = m;
    __syncthreads();
    const float amax = fmaxf(fmaxf(wm[0], wm[1]), fmaxf(wm[2], wm[3]));

    const float inv = (amax > 0.0f) ? (127.0f / amax) : 0.0f;
    if (t == 0) xscale[b] = (amax > 0.0f) ? (amax / 127.0f) : 1.0f;

    const int kc   = i0 >> 6;
    const int quad = (i0 >> 4) & 3;
    const int mt   = b >> 4;
    const int lane = (b & 15) | (quad << 4);

    i8 q[16];
#pragma unroll
    for (int j = 0; j < 16; ++j) {
        float r = rintf(vals[j] * inv);
        r = fminf(127.0f, fmaxf(-127.0f, r));
        q[j] = (i8)(int)r;
    }
    *(v4i*)(xq + ((size_t)(kc * 256 + mt * 64 + lane) * 16)) = *(const v4i*)q;
}

// ---------------------------------------------------------------------------
// GEMM. Block = n-tile (16 output rows); 8 waves split K into eighths.
// R2 change: pack int8 BEFORE LDS. Per wave-step:
//   - 4x global_load_dwordx4 raw int32 weights -> VGPR (same 4x256B coalesced
//     row runs as before)
//   - pack4 in registers (VALU count unchanged, just moved pre-LDS)
//   - 4x ds_write_b32 into a per-wave packed [16 rows][64 int8] 1KB tile
//     (bank = (grow*16+col)%32: 2-way, free) -- double buffered (2x1KB/wave)
//   - 1x ds_read_b128 = whole B-frag (row n, bytes q*16..+15; row stride 64B
//     -> 8-phase wave64 minimum, conflict-free, no swizzle)
// LDS traffic/wave-step: 8KB (R1: 4KB DMA-write + 4KB read) -> 2KB. R1 was
// LDS-pipe-bound: 16 waves x 8KB = 128KB/step-round @256B/clk ~ 512cyc vs
// 390cyc HBM -> matches measured ~36us. Now HBM-bound: ~30us expected.
// All waitcnts compiler-managed (register defs carry the deps; the manual
// vmcnt discipline was only needed for global_load_lds's def-less DMA).
// Cross-iter LDS WAR (write buf[x] after prior iter's read of buf[x]) is safe:
// per-wave DS ops process in issue order.
// LDS: staging 8x512 dwords overlaps combine region 8x1088 (barrier between).
// HBM: 180 MB weights (~28.6us floor) + 1 MB xq + 2.8 MB out.
// NOTE: timed window carries ~212us of harness poison fills (2x ~106us
// fillBufferAligned); controllable budget is ~46us.
// Next candidate if this lands: block-quantum imbalance (688 blocks = 2.69/CU,
// ceil 3 -> +11.6%) via 4-way split-K, ~ -2.5us more.
// ---------------------------------------------------------------------------
__global__ __launch_bounds__(512, 4)
void gemm_kernel(const int* __restrict__ wq, const i8* __restrict__ xq,
                 const float* __restrict__ xscale,
                 const float* __restrict__ wscale,
                 const float* __restrict__ bias,
                 float* __restrict__ out)
{
    __shared__ int lds[NWAVE * 1088];   // 34816 B; staging = first 4096 dwords
    const int lane = threadIdx.x & 63;
    const int wave = threadIdx.x >> 6;
    const int nt   = blockIdx.x;
    int* wbuf = lds + wave * 512;       // 2 x 256-dword packed tiles

    const int n    = lane & 15;     // B-fragment n / output col-in-tile
    const int q    = lane >> 4;     // B-fragment k-quad
    const int grow = lane >> 4;     // row-in-group for staging loads
    const int col  = lane & 15;     // 4-int8 slot within a row

    const int s0 = wave * SPW;      // this wave's first K-step
    const int* gbase = wq + (size_t)(nt * 16 + grow) * IN_F + s0 * 64 + col * 4;
    const v4i* pA = (const v4i*)xq + (size_t)s0 * 256 + lane;

    const int wdst = grow * 16 + col;   // + p*64: packed dword (4p+grow)*16+col
    const int roff = n * 16 + q * 4;    // B-frag read: row n, dwords q*4..q*4+3

    v4i acc[4];
#pragma unroll
    for (int mt = 0; mt < 4; ++mt) acc[mt] = (v4i){0, 0, 0, 0};

    v4i wB[4], aC[4], aN[4];

    // prologue: raw step0 -> regs; A(step0); pack+write buf0; issue step1
#pragma unroll
    for (int p = 0; p < 4; ++p)
        wB[p] = *(const v4i*)(gbase + (size_t)(4 * p) * IN_F);
#pragma unroll
    for (int mt = 0; mt < 4; ++mt) aC[mt] = pA[mt * 64];
#pragma unroll
    for (int p = 0; p < 4; ++p)
        wbuf[p * 64 + wdst] = pack4(wB[p][0], wB[p][1], wB[p][2], wB[p][3]);
#pragma unroll
    for (int p = 0; p < 4; ++p)
        wB[p] = *(const v4i*)(gbase + 64 + (size_t)(4 * p) * IN_F);
#pragma unroll
    for (int mt = 0; mt < 4; ++mt) aN[mt] = pA[256 + mt * 64];

#pragma unroll
    for (int ss = 0; ss < SPW; ++ss) {
        // B-fragment for step ss: one 16B read of packed bytes
        v4i bfrag = *(const v4i*)(wbuf + (ss & 1) * 256 + roff);

        if (ss + 1 < SPW) {
            // pack raw(ss+1) -> buf^1, then issue raw(ss+2)
            int* dst = wbuf + ((ss + 1) & 1) * 256;
#pragma unroll
            for (int p = 0; p < 4; ++p)
                dst[p * 64 + wdst] =
                    pack4(wB[p][0], wB[p][1], wB[p][2], wB[p][3]);
            if (ss + 2 < SPW) {
                const int* gs = gbase + (ss + 2) * 64;
#pragma unroll
                for (int p = 0; p < 4; ++p)
                    wB[p] = *(const v4i*)(gs + (size_t)(4 * p) * IN_F);
            }
        }

#pragma unroll
        for (int mt = 0; mt < 4; ++mt)
            acc[mt] = __builtin_amdgcn_mfma_i32_16x16x64_i8(aC[mt], bfrag,
                                                            acc[mt], 0, 0, 0);

        if (ss + 1 < SPW) {
#pragma unroll
            for (int mt = 0; mt < 4; ++mt) aC[mt] = aN[mt];
            if (ss + 2 < SPW) {
#pragma unroll
                for (int mt = 0; mt < 4; ++mt)
                    aN[mt] = pA[(ss + 2) * 256 + mt * 64];
            }
        }
    }

    // cross-wave combine: stride 17 (odd -> every bank 2x = free)
    __syncthreads();
#pragma unroll
    for (int mt = 0; mt < 4; ++mt)
#pragma unroll
        for (int r = 0; r < 4; ++r)
            lds[wave * 1088 + lane * 17 + mt * 4 + r] = acc[mt][r];
    __syncthreads();

    // 512 threads -> 1024 outputs: wave pair (mt2, rp) x lane (n, q) x 2 rows
    const int mt2 = wave >> 1;
    const int rp  = (wave & 1) * 2;
    const int o   = nt * 16 + n;
    const float wsc = wscale[o];
    const float bo  = bias[o];
#pragma unroll
    for (int j = 0; j < 2; ++j) {
        const int r = rp + j;
        int s = 0;
#pragma unroll
        for (int w = 0; w < NWAVE; ++w)
            s += lds[w * 1088 + lane * 17 + mt2 * 4 + r];
        const int b = mt2 * 16 + q * 4 + r;   // C/D: row = quad*4 + reg
        out[(size_t)b * OUT_F + o] = (float)s * xscale[b] * wsc + bo;
    }
}

extern "C" void kernel_launch(void* const* d_in, const int* in_sizes, int n_in,
                              void* d_out, int out_size, void* d_ws, size_t ws_size,
                              hipStream_t stream)
{
    const float* x      = (const float*)d_in[0];
    const int*   wq     = (const int*)d_in[1];   // integer inputs arrive as int32
    const float* wscale = (const float*)d_in[2];
    const float* bias   = (const float*)d_in[3];
    float* out = (float*)d_out;

    i8*    xq     = (i8*)d_ws;
    float* xscale = (float*)((char*)d_ws + 256u * 1024u);

    quant_x_kernel<<<BATCH, 256, 0, stream>>>(x, xq, xscale);
    gemm_kernel<<<NT, 512, 0, stream>>>(wq, xq, xscale, wscale, bias, out);
}

// Round 4
// 255.923 us; speedup vs baseline: 1.0231x; 1.0099x over previous
//
#include <hip/hip_runtime.h>

#define IN_F 4096
#define OUT_F 11008
#define BATCH 64
#define NT (OUT_F / 16)          // 688 n-tiles / blocks
#define NWAVE 8                  // waves per block
#define SPW (IN_F / 64 / NWAVE)  // 8 K-steps of 64 per wave

typedef int v4i __attribute__((ext_vector_type(4)));
typedef signed char i8;

__device__ __forceinline__ int pack4(int a0, int a1, int a2, int a3) {
    return (a0 & 0xff) | ((a1 & 0xff) << 8) | ((a2 & 0xff) << 16) |
           ((unsigned)a3 << 24);
}

// ---------------------------------------------------------------------------
// quant_x (proven layout): per-row int8 quantization of x into MFMA A-fragment
// order: xq v4i index (s*256 + mt*64 + lane) = A-frag(step s, m-tile mt, lane),
// A[m=lane&15][k=(lane>>4)*16+j]. shfl_xor reduce + 1 barrier.
// ---------------------------------------------------------------------------
__global__ __launch_bounds__(256)
void quant_x_kernel(const float* __restrict__ x, i8* __restrict__ xq,
                    float* __restrict__ xscale)
{
    const int b = blockIdx.x;
    const int t = threadIdx.x;
    const float* xr = x + (size_t)b * IN_F;
    const int i0 = t * 16;

    float vals[16];
    float m = 0.0f;
#pragma unroll
    for (int j = 0; j < 16; ++j) {
        vals[j] = xr[i0 + j];
        m = fmaxf(m, fabsf(vals[j]));
    }

#pragma unroll
    for (int o = 32; o > 0; o >>= 1) m = fmaxf(m, __shfl_xor(m, o));
    __shared__ float wm[4];
    if ((t & 63) == 0) wm[t >> 6] = m;
    __syncthreads();
    const float amax = fmaxf(fmaxf(wm[0], wm[1]), fmaxf(wm[2], wm[3]));

    const float inv = (amax > 0.0f) ? (127.0f / amax) : 0.0f;
    if (t == 0) xscale[b] = (amax > 0.0f) ? (amax / 127.0f) : 1.0f;

    const int kc   = i0 >> 6;
    const int quad = (i0 >> 4) & 3;
    const int mt   = b >> 4;
    const int lane = (b & 15) | (quad << 4);

    i8 q[16];
#pragma unroll
    for (int j = 0; j < 16; ++j) {
        float r = rintf(vals[j] * inv);
        r = fminf(127.0f, fmaxf(-127.0f, r));
        q[j] = (i8)(int)r;
    }
    *(v4i*)(xq + ((size_t)(kc * 256 + mt * 64 + lane) * 16)) = *(const v4i*)q;
}

// ---------------------------------------------------------------------------
// GEMM. Block = n-tile (16 output rows); 8 waves split K into eighths.
// R3/R4 change (unmeasured in R3 - container died, resubmitted verbatim):
// residency 2 -> 3 blocks/CU. R1/R2 were both 2 blocks/CU (512-block
// capacity < 688-block grid => 176-block tail round with the chip's HBM
// unsaturated). __launch_bounds__(512,6) caps VGPR at 85 (6 waves/EU,
// 24 waves/CU, 3 blocks/CU -> capacity 768 >= 688: whole grid resident in
// one dispatch round). To fit the cap the aN A-frag double-buffer is
// dropped (xq is L2/L3-resident; reload latency hidden by 24 waves/CU);
// wB keeps a 1-step lookahead.
// Steady state (chip-wide arithmetic): VALU ~1.3us equiv, MFMA ~2.3us,
// LDS trivial; HBM 183 MB fetch + 2.8 MB write => ~27.3us floor @6.8TB/s.
// Per wave-step: 4x global_load_dwordx4 (coalesced 256B runs) -> 4x pack4
// in regs -> 4x ds_write_b32 (2-way, free) into per-wave packed 1KB tile
// (double-buffered) -> 1x ds_read_b128 whole B-frag (row stride 64B =
// 8-phase wave64 minimum, conflict-free). Compiler-managed waitcnts.
// LDS: staging 8x512 dwords overlaps combine region 8x1088 (barrier between).
// NOTE: timed window carries ~212us of harness poison fills (2x ~106us
// fillBufferAligned @6.8TB/s); controllable budget ~46us. If this round is
// flat: 212 + ~29 gemm floor + ~8 quant/gaps == roofline, declare done.
// ---------------------------------------------------------------------------
__global__ __launch_bounds__(512, 6)
void gemm_kernel(const int* __restrict__ wq, const i8* __restrict__ xq,
                 const float* __restrict__ xscale,
                 const float* __restrict__ wscale,
                 const float* __restrict__ bias,
                 float* __restrict__ out)
{
    __shared__ int lds[NWAVE * 1088];   // 34816 B; staging = first 4096 dwords
    const int lane = threadIdx.x & 63;
    const int wave = threadIdx.x >> 6;
    const int nt   = blockIdx.x;
    int* wbuf = lds + wave * 512;       // 2 x 256-dword packed tiles

    const int n    = lane & 15;     // B-fragment n / output col-in-tile
    const int q    = lane >> 4;     // B-fragment k-quad
    const int grow = lane >> 4;     // row-in-group for staging loads
    const int col  = lane & 15;     // 4-int8 slot within a row

    const int s0 = wave * SPW;      // this wave's first K-step
    const int* gbase = wq + (size_t)(nt * 16 + grow) * IN_F + s0 * 64 + col * 4;
    const v4i* pA = (const v4i*)xq + (size_t)s0 * 256 + lane;

    const int wdst = grow * 16 + col;   // + p*64: packed dword (4p+grow)*16+col
    const int roff = n * 16 + q * 4;    // B-frag read: row n, dwords q*4..q*4+3

    v4i acc[4];
#pragma unroll
    for (int mt = 0; mt < 4; ++mt) acc[mt] = (v4i){0, 0, 0, 0};

    v4i wB[4], aC[4];

    // prologue: raw step0 -> regs; A(step0); pack+write buf0; issue step1
#pragma unroll
    for (int p = 0; p < 4; ++p)
        wB[p] = *(const v4i*)(gbase + (size_t)(4 * p) * IN_F);
#pragma unroll
    for (int mt = 0; mt < 4; ++mt) aC[mt] = pA[mt * 64];
#pragma unroll
    for (int p = 0; p < 4; ++p)
        wbuf[p * 64 + wdst] = pack4(wB[p][0], wB[p][1], wB[p][2], wB[p][3]);
#pragma unroll
    for (int p = 0; p < 4; ++p)
        wB[p] = *(const v4i*)(gbase + 64 + (size_t)(4 * p) * IN_F);

#pragma unroll
    for (int ss = 0; ss < SPW; ++ss) {
        // B-fragment for step ss: one 16B read of packed bytes
        v4i bfrag = *(const v4i*)(wbuf + (ss & 1) * 256 + roff);

        if (ss + 1 < SPW) {
            // pack raw(ss+1) -> buf^1, then issue raw(ss+2)
            int* dst = wbuf + ((ss + 1) & 1) * 256;
#pragma unroll
            for (int p = 0; p < 4; ++p)
                dst[p * 64 + wdst] =
                    pack4(wB[p][0], wB[p][1], wB[p][2], wB[p][3]);
            if (ss + 2 < SPW) {
                const int* gs = gbase + (ss + 2) * 64;
#pragma unroll
                for (int p = 0; p < 4; ++p)
                    wB[p] = *(const v4i*)(gs + (size_t)(4 * p) * IN_F);
            }
        }

#pragma unroll
        for (int mt = 0; mt < 4; ++mt)
            acc[mt] = __builtin_amdgcn_mfma_i32_16x16x64_i8(aC[mt], bfrag,
                                                            acc[mt], 0, 0, 0);

        // reload A-frags for next step after the MFMAs consume aC
        // (xq is L2/L3-resident; latency covered by 24 waves/CU)
        if (ss + 1 < SPW) {
#pragma unroll
            for (int mt = 0; mt < 4; ++mt)
                aC[mt] = pA[(ss + 1) * 256 + mt * 64];
        }
    }

    // cross-wave combine: stride 17 (odd -> every bank 2x = free)
    __syncthreads();
#pragma unroll
    for (int mt = 0; mt < 4; ++mt)
#pragma unroll
        for (int r = 0; r < 4; ++r)
            lds[wave * 1088 + lane * 17 + mt * 4 + r] = acc[mt][r];
    __syncthreads();

    // 512 threads -> 1024 outputs: wave pair (mt2, rp) x lane (n, q) x 2 rows
    const int mt2 = wave >> 1;
    const int rp  = (wave & 1) * 2;
    const int o   = nt * 16 + n;
    const float wsc = wscale[o];
    const float bo  = bias[o];
#pragma unroll
    for (int j = 0; j < 2; ++j) {
        const int r = rp + j;
        int s = 0;
#pragma unroll
        for (int w = 0; w < NWAVE; ++w)
            s += lds[w * 1088 + lane * 17 + mt2 * 4 + r];
        const int b = mt2 * 16 + q * 4 + r;   // C/D: row = quad*4 + reg
        out[(size_t)b * OUT_F + o] = (float)s * xscale[b] * wsc + bo;
    }
}

extern "C" void kernel_launch(void* const* d_in, const int* in_sizes, int n_in,
                              void* d_out, int out_size, void* d_ws, size_t ws_size,
                              hipStream_t stream)
{
    const float* x      = (const float*)d_in[0];
    const int*   wq     = (const int*)d_in[1];   // integer inputs arrive as int32
    const float* wscale = (const float*)d_in[2];
    const float* bias   = (const float*)d_in[3];
    float* out = (float*)d_out;

    i8*    xq     = (i8*)d_ws;
    float* xscale = (float*)((char*)d_ws + 256u * 1024u);

    quant_x_kernel<<<BATCH, 256, 0, stream>>>(x, xq, xscale);
    gemm_kernel<<<NT, 512, 0, stream>>>(wq, xq, xscale, wscale, bias, out);
}